// Round 4
// baseline (812.354 us; speedup 1.0000x reference)
//
#include <hip/hip_runtime.h>
#include <cstdint>
#include <cstddef>

typedef __attribute__((ext_vector_type(4))) float f32x4;
typedef __attribute__((ext_vector_type(8))) __bf16 bf16x8;
typedef __attribute__((ext_vector_type(4))) unsigned int u32x4;
typedef __attribute__((ext_vector_type(2))) unsigned int u32x2;

#define DEVFN static __device__ __forceinline__

// ---------------- workspace layout (bytes) ----------------
#define OFF_XBF    0ull                 // bf16 x          8192x1024
#define OFF_WINBF  16777216ull          // bf16 W_in       4096x1024
#define OFF_WXBF   25165824ull          // bf16 W_x        32x2048
#define OFF_WOUTBF 25296896ull          // bf16 W_out      1024x2048
#define OFF_WRED   29491200ull          // f32  W_red      1024x16
#define OFF_XIBF   29556736ull          // bf16 xi         8192x2048
#define OFF_RESBF  63111168ull          // bf16 res        8192x2048
#define OFF_XSBF   96665600ull          // bf16 xs         8192x2048
#define OFF_BC     130220032ull         // f32  bc         8192x32
#define OFF_HS     131268608ull         // f32  hs         8192x16

DEVFN unsigned short f2bf(float f) {
  unsigned u = __float_as_uint(f);
  return (unsigned short)((u + 0x7FFFu + ((u >> 16) & 1u)) >> 16);
}

DEVFN void gload_lds16(const void* g, void* l) {
  __builtin_amdgcn_global_load_lds(
      (const __attribute__((address_space(1))) void*)g,
      (__attribute__((address_space(3))) void*)l, 16, 0, 0);
}

// DPP lane permute within 16-lane rows (all lanes active). XOR masks:
//  0xB1 quad_perm[1,0,3,2]=xor1, 0x4E [2,3,0,1]=xor2, 0x1B [3,2,1,0]=xor3,
//  0x141 ROW_HALF_MIRROR=xor7, 0x140 ROW_MIRROR=xor15.
#define DPPF(x, ctrl) \
  __int_as_float(__builtin_amdgcn_update_dpp(0, __float_as_int(x), ctrl, 0xF, 0xF, true))

// ---------------- prep: f32->bf16 converts + W_red, one launch ----------------
DEVFN void cvt8(const float* __restrict__ in, unsigned short* __restrict__ out, int t) {
  f32x4 a = *(const f32x4*)(in + (size_t)t * 8);
  f32x4 b = *(const f32x4*)(in + (size_t)t * 8 + 4);
  u32x4 r;
  r.x = (unsigned)f2bf(a[0]) | ((unsigned)f2bf(a[1]) << 16);
  r.y = (unsigned)f2bf(a[2]) | ((unsigned)f2bf(a[3]) << 16);
  r.z = (unsigned)f2bf(b[0]) | ((unsigned)f2bf(b[1]) << 16);
  r.w = (unsigned)f2bf(b[2]) | ((unsigned)f2bf(b[3]) << 16);
  *(u32x4*)(out + (size_t)t * 8) = r;
}

__global__ __launch_bounds__(256) void k_prep(
    const float* __restrict__ x, const float* __restrict__ W_in,
    const float* __restrict__ W_x, const float* __restrict__ W_out,
    unsigned short* __restrict__ xbf, unsigned short* __restrict__ winbf,
    unsigned short* __restrict__ wxbf, unsigned short* __restrict__ woutbf,
    float* __restrict__ wred) {
  const int bid = blockIdx.x, tid = threadIdx.x;
  if (bid < 4096)      cvt8(x,     xbf,    bid * 256 + tid);
  else if (bid < 6144) cvt8(W_in,  winbf,  (bid - 4096) * 256 + tid);
  else if (bid < 6176) cvt8(W_x,   wxbf,   (bid - 6144) * 256 + tid);
  else if (bid < 7200) cvt8(W_out, woutbf, (bid - 6176) * 256 + tid);
  else {
    // W_red[m][j] = sum_{r<128} W_out[m][r*16+j]
    const int t = (bid - 7200) * 256 + tid;   // 16384 threads
    const int m = t >> 4, j = t & 15;
    float s = 0.f;
    for (int r = 0; r < 128; r++) s += W_out[(size_t)m * 2048 + r * 16 + j];
    wred[t] = s;
  }
}

// ---------------- bf16 NT MFMA GEMM core: C[M,N] = A[M,K] * B[N,K]^T --------
// 128x128 tile, BK=64, 4 waves (2x2), mfma_f32_16x16x32_bf16, linear LDS,
// global_load_lds width=16 (m97 structure).
template <int EPI>
DEVFN void gemm128(const unsigned short* __restrict__ Ag,
                   const unsigned short* __restrict__ Bg, int K,
                   int m0, int n0, const float* __restrict__ bias,
                   float* __restrict__ outf,
                   unsigned short* __restrict__ ob0,   // EPI0: cols [0,2048) bf16
                   unsigned short* __restrict__ ob1) { // EPI0: cols [2048,4096) bf16
  __shared__ unsigned short As[128 * 64];
  __shared__ unsigned short Bs[128 * 64];
  const int tid = threadIdx.x;
  const int wave = tid >> 6, lane = tid & 63;
  const int wm = wave >> 1, wn = wave & 1;
  const int fr = lane & 15;            // row-within-16 of A/B fragment
  const int k8 = (lane >> 4) << 3;     // k offset (8 contiguous bf16 per lane)

  f32x4 acc[4][4];
#pragma unroll
  for (int a = 0; a < 4; a++)
#pragma unroll
    for (int b = 0; b < 4; b++) acc[a][b] = f32x4{0.f, 0.f, 0.f, 0.f};

  for (int kt = 0; kt < K; kt += 64) {
#pragma unroll
    for (int i = 0; i < 4; i++) {
      const int base = (wave << 10) + (i << 12);      // byte offset in 16KB tile
      const int off = base + (lane << 4);
      const int row = off >> 7;
      const int col = (off & 127) >> 1;
      gload_lds16(Ag + (size_t)(m0 + row) * K + kt + col, (char*)As + base);
      gload_lds16(Bg + (size_t)(n0 + row) * K + kt + col, (char*)Bs + base);
    }
    __syncthreads();
#pragma unroll
    for (int kk = 0; kk < 2; kk++) {
      bf16x8 af[4], bfr[4];
#pragma unroll
      for (int f = 0; f < 4; f++) {
        af[f]  = *(const bf16x8*)&As[(wm * 64 + f * 16 + fr) * 64 + kk * 32 + k8];
        bfr[f] = *(const bf16x8*)&Bs[(wn * 64 + f * 16 + fr) * 64 + kk * 32 + k8];
      }
#pragma unroll
      for (int fi = 0; fi < 4; fi++)
#pragma unroll
        for (int fj = 0; fj < 4; fj++)
          acc[fi][fj] = __builtin_amdgcn_mfma_f32_16x16x32_bf16(
              af[fi], bfr[fj], acc[fi][fj], 0, 0, 0);
    }
    __syncthreads();
  }

  // epilogue: C/D layout col=lane&15, row=(lane>>4)*4+r (m89-verified)
  const int r0 = (lane >> 4) * 4;
#pragma unroll
  for (int fj = 0; fj < 4; fj++) {
    const int col = n0 + wn * 64 + fj * 16 + fr;
    const float bia = (EPI == 0) ? bias[col] : 0.f;
#pragma unroll
    for (int fi = 0; fi < 4; fi++) {
      const int rowb = m0 + wm * 64 + fi * 16 + r0;
#pragma unroll
      for (int r = 0; r < 4; r++) {
        const float v = acc[fi][fj][r] + bia;
        if (EPI == 0) {
          if (col < 2048) ob0[(size_t)(rowb + r) * 2048 + col] = f2bf(v);
          else            ob1[(size_t)(rowb + r) * 2048 + (col - 2048)] = f2bf(v);
        } else {
          outf[(size_t)(rowb + r) * 1024 + col] = v;
        }
      }
    }
  }
}

// K1: in_proj  C1 = x_bf @ W_in^T + b_in, split-store xi(bf16) / res(bf16)
__global__ __launch_bounds__(256) void k_gemm1(const unsigned short* __restrict__ xbf,
                                               const unsigned short* __restrict__ winbf,
                                               const float* __restrict__ b_in,
                                               unsigned short* __restrict__ xibf,
                                               unsigned short* __restrict__ resbf) {
  const int bid = blockIdx.x;                // 64 x 32 tiles
  gemm128<0>(xbf, winbf, 1024, (bid >> 5) * 128, (bid & 31) * 128, b_in,
             nullptr, xibf, resbf);
}

// K2: depthwise causal conv (K=4) + silu; xi bf16 -> xs bf16
__global__ __launch_bounds__(256) void k_conv(const unsigned short* __restrict__ xi,
                                              const float* __restrict__ cw,
                                              const float* __restrict__ cb,
                                              unsigned short* __restrict__ xs) {
  const int t = blockIdx.x * 256 + threadIdx.x;
  const int c4 = t & 511;                 // 512 channel-quads
  const int lc = (t >> 9) & 255;          // 256 l-chunks of 8
  const int b  = t >> 17;                 // 4 batches
  const int l0 = lc * 8;
  const int c0 = c4 * 4;
  const unsigned short* xb = xi + ((size_t)(b * 2048 + l0)) * 2048 + c0;
  u32x2 raw[11];
#pragma unroll
  for (int j = 0; j < 11; j++) {
    const int l = l0 + j - 3;
    raw[j] = (l >= 0) ? *(const u32x2*)(xb + ((long)j - 3) * 2048) : u32x2{0u, 0u};
  }
  f32x4 val[11];
#pragma unroll
  for (int j = 0; j < 11; j++) {
    val[j][0] = __uint_as_float(raw[j].x << 16);
    val[j][1] = __uint_as_float(raw[j].x & 0xFFFF0000u);
    val[j][2] = __uint_as_float(raw[j].y << 16);
    val[j][3] = __uint_as_float(raw[j].y & 0xFFFF0000u);
  }
  const f32x4 w0 = *(const f32x4*)(cw + (size_t)c0 * 4);
  const f32x4 w1 = *(const f32x4*)(cw + (size_t)(c0 + 1) * 4);
  const f32x4 w2 = *(const f32x4*)(cw + (size_t)(c0 + 2) * 4);
  const f32x4 w3 = *(const f32x4*)(cw + (size_t)(c0 + 3) * 4);
  const f32x4 bb = *(const f32x4*)(cb + c0);
  unsigned short* xp = xs + ((size_t)(b * 2048 + l0)) * 2048 + c0;
#pragma unroll
  for (int jo = 0; jo < 8; jo++) {
    f32x4 v;
    v[0] = bb[0] + w0[0]*val[jo][0] + w0[1]*val[jo+1][0] + w0[2]*val[jo+2][0] + w0[3]*val[jo+3][0];
    v[1] = bb[1] + w1[0]*val[jo][1] + w1[1]*val[jo+1][1] + w1[2]*val[jo+2][1] + w1[3]*val[jo+3][1];
    v[2] = bb[2] + w2[0]*val[jo][2] + w2[1]*val[jo+1][2] + w2[2]*val[jo+2][2] + w2[3]*val[jo+3][2];
    v[3] = bb[3] + w3[0]*val[jo][3] + w3[1]*val[jo+1][3] + w3[2]*val[jo+2][3] + w3[3]*val[jo+3][3];
#pragma unroll
    for (int q = 0; q < 4; q++) {
      const float x = v[q];
      v[q] = x * __builtin_amdgcn_rcpf(1.f + __expf(-x));   // silu
    }
    u32x2 rr;
    rr.x = (unsigned)f2bf(v[0]) | ((unsigned)f2bf(v[1]) << 16);
    rr.y = (unsigned)f2bf(v[2]) | ((unsigned)f2bf(v[3]) << 16);
    *(u32x2*)(xp + (size_t)jo * 2048) = rr;
  }
}

// K3: x_proj  bc = xs @ W_x^T + b_x   (M=8192, N=32, K=2048)
__global__ __launch_bounds__(256) void k_gemm2(const unsigned short* __restrict__ xs,
                                               const unsigned short* __restrict__ wx,
                                               const float* __restrict__ bx,
                                               float* __restrict__ bc) {
  __shared__ unsigned short As[128 * 64];
  __shared__ unsigned short Bs[32 * 64];
  const int tid = threadIdx.x, wave = tid >> 6, lane = tid & 63;
  const int m0 = blockIdx.x * 128;
  const int fr = lane & 15, k8 = (lane >> 4) << 3;
  f32x4 acc[2][2];
#pragma unroll
  for (int a = 0; a < 2; a++)
#pragma unroll
    for (int b = 0; b < 2; b++) acc[a][b] = f32x4{0.f, 0.f, 0.f, 0.f};

  for (int kt = 0; kt < 2048; kt += 64) {
#pragma unroll
    for (int i = 0; i < 4; i++) {
      const int base = (wave << 10) + (i << 12);
      const int off = base + (lane << 4);
      const int row = off >> 7, col = (off & 127) >> 1;
      gload_lds16(xs + (size_t)(m0 + row) * 2048 + kt + col, (char*)As + base);
    }
    {
      const int base = (wave << 10);
      const int off = base + (lane << 4);
      const int row = off >> 7, col = (off & 127) >> 1;
      gload_lds16(wx + (size_t)row * 2048 + kt + col, (char*)Bs + base);
    }
    __syncthreads();
#pragma unroll
    for (int kk = 0; kk < 2; kk++) {
      bf16x8 af[2], bfr[2];
#pragma unroll
      for (int f = 0; f < 2; f++) {
        af[f]  = *(const bf16x8*)&As[(wave * 32 + f * 16 + fr) * 64 + kk * 32 + k8];
        bfr[f] = *(const bf16x8*)&Bs[(f * 16 + fr) * 64 + kk * 32 + k8];
      }
#pragma unroll
      for (int fi = 0; fi < 2; fi++)
#pragma unroll
        for (int fj = 0; fj < 2; fj++)
          acc[fi][fj] = __builtin_amdgcn_mfma_f32_16x16x32_bf16(
              af[fi], bfr[fj], acc[fi][fj], 0, 0, 0);
    }
    __syncthreads();
  }
  const int r0 = (lane >> 4) * 4;
#pragma unroll
  for (int fi = 0; fi < 2; fi++)
#pragma unroll
    for (int fj = 0; fj < 2; fj++) {
      const int col = fj * 16 + fr;
      const float bia = bx[col];
#pragma unroll
      for (int r = 0; r < 4; r++) {
        const int row = m0 + wave * 32 + fi * 16 + r0 + r;
        bc[(size_t)row * 32 + col] = acc[fi][fj][r] + bia;
      }
    }
}

// ---------------- scan step: h' = tanh(A_t h + B*h + C), DPP broadcast ------
// a[q][r] = A_t[i][i ^ (q*4+r)];  hx[m] = h[i^m] generated with 15 v_mov_dpp.
DEVFN float dpp_step(float h, const f32x4& a0, const f32x4& a1,
                     const f32x4& a2, const f32x4& a3, float Bt, float Ct) {
  const float x1 = DPPF(h, 0xB1);   // xor1
  const float x2 = DPPF(h, 0x4E);   // xor2
  const float x3 = DPPF(h, 0x1B);   // xor3
  const float m7 = DPPF(h, 0x141);  // xor7
  const float x6 = DPPF(m7, 0xB1);  // xor6
  const float x5 = DPPF(m7, 0x4E);  // xor5
  const float x4 = DPPF(m7, 0x1B);  // xor4
  const float mF = DPPF(h, 0x140);  // xor15
  const float xE = DPPF(mF, 0xB1);  // xor14
  const float xD = DPPF(mF, 0x4E);  // xor13
  const float xC = DPPF(mF, 0x1B);  // xor12
  const float m8 = DPPF(mF, 0x141); // xor8
  const float x9 = DPPF(m8, 0xB1);  // xor9
  const float xA = DPPF(m8, 0x4E);  // xor10
  const float xB = DPPF(m8, 0x1B);  // xor11
  float s0 = fmaf(a0[0], h, fmaf(Bt, h, Ct));
  s0 = fmaf(a0[1], x1, s0); s0 = fmaf(a0[2], x2, s0); s0 = fmaf(a0[3], x3, s0);
  float s1 = a1[0] * x4;
  s1 = fmaf(a1[1], x5, s1); s1 = fmaf(a1[2], x6, s1); s1 = fmaf(a1[3], m7, s1);
  float s2 = a2[0] * m8;
  s2 = fmaf(a2[1], x9, s2); s2 = fmaf(a2[2], xA, s2); s2 = fmaf(a2[3], xB, s2);
  float s3 = a3[0] * xC;
  s3 = fmaf(a3[1], xD, s3); s3 = fmaf(a3[2], xE, s3); s3 = fmaf(a3[3], mF, s3);
  const float s = (s0 + s1) + (s2 + s3);
  // tanh(s) = 1 - 2/(exp(2s)+1); exp->inf / ->0 give +-1 correctly
  const float e = __expf(2.f * s);
  return fmaf(-2.f, __builtin_amdgcn_rcpf(e + 1.f), 1.f);
}

// K4: fused  [blocks 0..511]: out = res_bf @ W_out^T   (MFMA)
//            [block 512, wave 0]: sequential selective scan -> hs
__global__ __launch_bounds__(256) void k4_gemm3_scan(
    const unsigned short* __restrict__ resbf, const unsigned short* __restrict__ woutbf,
    float* __restrict__ out, const float* __restrict__ bc, const float* __restrict__ dt,
    const float* __restrict__ Amat, float* __restrict__ hs) {
  if (blockIdx.x < 512) {
    const int bid = blockIdx.x;              // 64 x 8 tiles
    gemm128<1>(resbf, woutbf, 2048, (bid >> 3) * 128, (bid & 7) * 128, nullptr,
               out, nullptr, nullptr);
    return;
  }
  // AxL[p*256 + q*64 + i*4 + r] = exp(exp(dt[p]) * A[i][i^(4q+r)])
  __shared__ float AxL[16 * 16 * 16];
  if (threadIdx.x >= 64) return;             // single wave does the scan
  const int lane = threadIdx.x, b = lane >> 4, i = lane & 15;
  for (int t = lane; t < 4096; t += 64) {
    const int p = t >> 8, q = (t >> 6) & 3, ii = (t >> 2) & 15, r = t & 3;
    const int m = q * 4 + r;
    AxL[t] = __expf(__expf(dt[p]) * Amat[ii * 16 + (ii ^ m)]);
  }
  asm volatile("s_waitcnt lgkmcnt(0)" ::: "memory");
  __builtin_amdgcn_wave_barrier();

  const float* bcp = bc + (size_t)b * 2048 * 32 + i;   // B at [l*32], C at [l*32+16]
  const float* axi = AxL + (i << 2);
  float* hsp = hs + (size_t)b * 2048 * 16 + i;
  float h = 0.f;

  // B/C double half-buffers, prefetched ~8 steps ahead
  float h0B[8], h0C[8], h1B[8], h1C[8];
#pragma unroll
  for (int q = 0; q < 8; q++) { h0B[q] = bcp[q * 32]; h0C[q] = bcp[q * 32 + 16]; }
  // preload A-coeffs for p=0
  f32x4 ax0 = *(const f32x4*)(axi);
  f32x4 ax1 = *(const f32x4*)(axi + 64);
  f32x4 ax2 = *(const f32x4*)(axi + 128);
  f32x4 ax3 = *(const f32x4*)(axi + 192);

  for (int l0 = 0; l0 < 2048; l0 += 16) {
    {
      const float* bq = bcp + (size_t)(l0 + 8) * 32;
#pragma unroll
      for (int q = 0; q < 8; q++) { h1B[q] = bq[q * 32]; h1C[q] = bq[q * 32 + 16]; }
    }
#pragma unroll
    for (int q = 0; q < 8; q++) {
      const float* axn = axi + (q + 1) * 256;          // p = q+1 (compile-time)
      const f32x4 n0 = *(const f32x4*)(axn);
      const f32x4 n1 = *(const f32x4*)(axn + 64);
      const f32x4 n2 = *(const f32x4*)(axn + 128);
      const f32x4 n3 = *(const f32x4*)(axn + 192);
      h = dpp_step(h, ax0, ax1, ax2, ax3, h0B[q], h0C[q]);
      hsp[(size_t)(l0 + q) * 16] = h;
      ax0 = n0; ax1 = n1; ax2 = n2; ax3 = n3;
    }
    {
      const float* bq = bcp + (size_t)((l0 + 16) & 2047) * 32;  // wrap: last unused
#pragma unroll
      for (int q = 0; q < 8; q++) { h0B[q] = bq[q * 32]; h0C[q] = bq[q * 32 + 16]; }
    }
#pragma unroll
    for (int q = 8; q < 16; q++) {
      const float* axn = axi + ((q + 1) & 15) * 256;   // p = 9..15,0 (compile-time)
      const f32x4 n0 = *(const f32x4*)(axn);
      const f32x4 n1 = *(const f32x4*)(axn + 64);
      const f32x4 n2 = *(const f32x4*)(axn + 128);
      const f32x4 n3 = *(const f32x4*)(axn + 192);
      h = dpp_step(h, ax0, ax1, ax2, ax3, h1B[q - 8], h1C[q - 8]);
      hsp[(size_t)(l0 + q) * 16] = h;
      ax0 = n0; ax1 = n1; ax2 = n2; ax3 = n3;
    }
  }
}

// K5: out += b_out + hs @ W_red^T   (tile(hs,128) @ W_out^T == hs @ W_red^T)
__global__ __launch_bounds__(256) void k5_combine(float* __restrict__ out,
                                                  const float* __restrict__ hs,
                                                  const float* __restrict__ wred,
                                                  const float* __restrict__ bo) {
  const int m4 = threadIdx.x;      // 256 col-quads
  const int rg = blockIdx.x;       // 2048 row-quads
  f32x4 w[4][4];
#pragma unroll
  for (int mi = 0; mi < 4; mi++)
#pragma unroll
    for (int q = 0; q < 4; q++)
      w[mi][q] = *(const f32x4*)&wred[(size_t)(m4 * 4 + mi) * 16 + q * 4];
  const f32x4 bov = *(const f32x4*)&bo[m4 * 4];
#pragma unroll
  for (int r = 0; r < 4; r++) {
    const size_t row = (size_t)rg * 4 + r;
    f32x4 hv[4];
#pragma unroll
    for (int q = 0; q < 4; q++) hv[q] = *(const f32x4*)&hs[row * 16 + q * 4];
    float* op = out + row * 1024 + m4 * 4;
    f32x4 o = *(f32x4*)op;
#pragma unroll
    for (int mi = 0; mi < 4; mi++) {
      float v = bov[mi];
#pragma unroll
      for (int q = 0; q < 4; q++)
        v += w[mi][q][0]*hv[q][0] + w[mi][q][1]*hv[q][1] +
             w[mi][q][2]*hv[q][2] + w[mi][q][3]*hv[q][3];
      o[mi] += v;
    }
    *(f32x4*)op = o;
  }
}

extern "C" void kernel_launch(void* const* d_in, const int* in_sizes, int n_in,
                              void* d_out, int out_size, void* d_ws, size_t ws_size,
                              hipStream_t stream) {
  const float* x      = (const float*)d_in[0];
  const float* W_in   = (const float*)d_in[1];
  const float* b_in   = (const float*)d_in[2];
  const float* conv_w = (const float*)d_in[3];
  const float* conv_b = (const float*)d_in[4];
  const float* W_x    = (const float*)d_in[5];
  const float* b_x    = (const float*)d_in[6];
  const float* dt     = (const float*)d_in[7];
  const float* A      = (const float*)d_in[8];
  const float* W_out  = (const float*)d_in[10];
  const float* b_out  = (const float*)d_in[11];
  float* out = (float*)d_out;

  char* ws = (char*)d_ws;
  unsigned short* xbf    = (unsigned short*)(ws + OFF_XBF);
  unsigned short* winbf  = (unsigned short*)(ws + OFF_WINBF);
  unsigned short* wxbf   = (unsigned short*)(ws + OFF_WXBF);
  unsigned short* woutbf = (unsigned short*)(ws + OFF_WOUTBF);
  float*          wred   = (float*)(ws + OFF_WRED);
  unsigned short* xibf   = (unsigned short*)(ws + OFF_XIBF);
  unsigned short* resbf  = (unsigned short*)(ws + OFF_RESBF);
  unsigned short* xsbf   = (unsigned short*)(ws + OFF_XSBF);
  float*          bc     = (float*)(ws + OFF_BC);
  float*          hsb    = (float*)(ws + OFF_HS);

  k_prep<<<7264, 256, 0, stream>>>(x, W_in, W_x, W_out, xbf, winbf, wxbf, woutbf, wred);
  k_gemm1<<<2048, 256, 0, stream>>>(xbf, winbf, b_in, xibf, resbf);
  k_conv<<<2048, 256, 0, stream>>>(xibf, conv_w, conv_b, xsbf);
  k_gemm2<<<64, 256, 0, stream>>>(xsbf, wxbf, b_x, bc);
  k4_gemm3_scan<<<513, 256, 0, stream>>>(resbf, woutbf, out, bc, dt, A, hsb);
  k5_combine<<<2048, 256, 0, stream>>>(out, hsb, wred, b_out);
}

// Round 5
// 516.785 us; speedup vs baseline: 1.5719x; 1.5719x over previous
//
#include <hip/hip_runtime.h>
#include <cstdint>
#include <cstddef>

typedef __attribute__((ext_vector_type(4))) float f32x4;
typedef __attribute__((ext_vector_type(8))) __bf16 bf16x8;
typedef __attribute__((ext_vector_type(4))) unsigned int u32x4;
typedef __attribute__((ext_vector_type(2))) unsigned int u32x2;

#define DEVFN static __device__ __forceinline__

// ---------------- workspace layout (bytes) ----------------
#define OFF_XBF    0ull                 // bf16 x          8192x1024
#define OFF_WINBF  16777216ull          // bf16 W_in       4096x1024
#define OFF_WXBF   25165824ull          // bf16 W_x        32x2048
#define OFF_WOUTBF 25296896ull          // bf16 W_out      1024x2048
#define OFF_WRED   29491200ull          // f32  W_red      1024x16
#define OFF_XIBF   29556736ull          // bf16 xi         8192x2048
#define OFF_RESBF  63111168ull          // bf16 res        8192x2048
#define OFF_XSBF   96665600ull          // bf16 xs         8192x2048
#define OFF_BC     130220032ull         // f32  bc         8192x32
#define OFF_HS     131268608ull         // f32  hs         8192x16

DEVFN unsigned short f2bf(float f) {
  unsigned u = __float_as_uint(f);
  return (unsigned short)((u + 0x7FFFu + ((u >> 16) & 1u)) >> 16);
}

DEVFN void gload_lds16(const void* g, void* l) {
  __builtin_amdgcn_global_load_lds(
      (const __attribute__((address_space(1))) void*)g,
      (__attribute__((address_space(3))) void*)l, 16, 0, 0);
}

// DPP quad_perm (within groups of 4 lanes): 0xB1 = [1,0,3,2] (xor1),
// 0x4E = [2,3,0,1] (xor2).
#define DPPF(x, ctrl) \
  __int_as_float(__builtin_amdgcn_update_dpp(0, __float_as_int(x), ctrl, 0xF, 0xF, true))

// ---------------- prep: f32->bf16 converts + W_red, one launch ----------------
DEVFN void cvt8(const float* __restrict__ in, unsigned short* __restrict__ out, int t) {
  f32x4 a = *(const f32x4*)(in + (size_t)t * 8);
  f32x4 b = *(const f32x4*)(in + (size_t)t * 8 + 4);
  u32x4 r;
  r.x = (unsigned)f2bf(a[0]) | ((unsigned)f2bf(a[1]) << 16);
  r.y = (unsigned)f2bf(a[2]) | ((unsigned)f2bf(a[3]) << 16);
  r.z = (unsigned)f2bf(b[0]) | ((unsigned)f2bf(b[1]) << 16);
  r.w = (unsigned)f2bf(b[2]) | ((unsigned)f2bf(b[3]) << 16);
  *(u32x4*)(out + (size_t)t * 8) = r;
}

__global__ __launch_bounds__(256) void k_prep(
    const float* __restrict__ x, const float* __restrict__ W_in,
    const float* __restrict__ W_x, const float* __restrict__ W_out,
    unsigned short* __restrict__ xbf, unsigned short* __restrict__ winbf,
    unsigned short* __restrict__ wxbf, unsigned short* __restrict__ woutbf,
    float* __restrict__ wred) {
  const int bid = blockIdx.x, tid = threadIdx.x;
  if (bid < 4096)      cvt8(x,     xbf,    bid * 256 + tid);
  else if (bid < 6144) cvt8(W_in,  winbf,  (bid - 4096) * 256 + tid);
  else if (bid < 6176) cvt8(W_x,   wxbf,   (bid - 6144) * 256 + tid);
  else if (bid < 7200) cvt8(W_out, woutbf, (bid - 6176) * 256 + tid);
  else {
    // W_red[m][j] = sum_{r<128} W_out[m][r*16+j]
    const int t = (bid - 7200) * 256 + tid;   // 16384 threads
    const int m = t >> 4, j = t & 15;
    float s = 0.f;
    for (int r = 0; r < 128; r++) s += W_out[(size_t)m * 2048 + r * 16 + j];
    wred[t] = s;
  }
}

// ---------------- bf16 NT MFMA GEMM core: C[M,N] = A[M,K] * B[N,K]^T --------
// 128x128 tile, BK=64, 4 waves (2x2), mfma_f32_16x16x32_bf16, linear LDS,
// global_load_lds width=16 (m97 structure).
template <int EPI>
DEVFN void gemm128(const unsigned short* __restrict__ Ag,
                   const unsigned short* __restrict__ Bg, int K,
                   int m0, int n0, const float* __restrict__ bias,
                   float* __restrict__ outf,
                   unsigned short* __restrict__ ob0,   // EPI0: cols [0,2048) bf16
                   unsigned short* __restrict__ ob1) { // EPI0: cols [2048,4096) bf16
  __shared__ unsigned short As[128 * 64];
  __shared__ unsigned short Bs[128 * 64];
  const int tid = threadIdx.x;
  const int wave = tid >> 6, lane = tid & 63;
  const int wm = wave >> 1, wn = wave & 1;
  const int fr = lane & 15;            // row-within-16 of A/B fragment
  const int k8 = (lane >> 4) << 3;     // k offset (8 contiguous bf16 per lane)

  f32x4 acc[4][4];
#pragma unroll
  for (int a = 0; a < 4; a++)
#pragma unroll
    for (int b = 0; b < 4; b++) acc[a][b] = f32x4{0.f, 0.f, 0.f, 0.f};

  for (int kt = 0; kt < K; kt += 64) {
#pragma unroll
    for (int i = 0; i < 4; i++) {
      const int base = (wave << 10) + (i << 12);      // byte offset in 16KB tile
      const int off = base + (lane << 4);
      const int row = off >> 7;
      const int col = (off & 127) >> 1;
      gload_lds16(Ag + (size_t)(m0 + row) * K + kt + col, (char*)As + base);
      gload_lds16(Bg + (size_t)(n0 + row) * K + kt + col, (char*)Bs + base);
    }
    __syncthreads();
#pragma unroll
    for (int kk = 0; kk < 2; kk++) {
      bf16x8 af[4], bfr[4];
#pragma unroll
      for (int f = 0; f < 4; f++) {
        af[f]  = *(const bf16x8*)&As[(wm * 64 + f * 16 + fr) * 64 + kk * 32 + k8];
        bfr[f] = *(const bf16x8*)&Bs[(wn * 64 + f * 16 + fr) * 64 + kk * 32 + k8];
      }
#pragma unroll
      for (int fi = 0; fi < 4; fi++)
#pragma unroll
        for (int fj = 0; fj < 4; fj++)
          acc[fi][fj] = __builtin_amdgcn_mfma_f32_16x16x32_bf16(
              af[fi], bfr[fj], acc[fi][fj], 0, 0, 0);
    }
    __syncthreads();
  }

  // epilogue: C/D layout col=lane&15, row=(lane>>4)*4+r (m89-verified)
  const int r0 = (lane >> 4) * 4;
#pragma unroll
  for (int fj = 0; fj < 4; fj++) {
    const int col = n0 + wn * 64 + fj * 16 + fr;
    const float bia = (EPI == 0) ? bias[col] : 0.f;
#pragma unroll
    for (int fi = 0; fi < 4; fi++) {
      const int rowb = m0 + wm * 64 + fi * 16 + r0;
#pragma unroll
      for (int r = 0; r < 4; r++) {
        const float v = acc[fi][fj][r] + bia;
        if (EPI == 0) {
          if (col < 2048) ob0[(size_t)(rowb + r) * 2048 + col] = f2bf(v);
          else            ob1[(size_t)(rowb + r) * 2048 + (col - 2048)] = f2bf(v);
        } else {
          outf[(size_t)(rowb + r) * 1024 + col] = v;
        }
      }
    }
  }
}

// K1: in_proj  C1 = x_bf @ W_in^T + b_in, split-store xi(bf16) / res(bf16)
__global__ __launch_bounds__(256) void k_gemm1(const unsigned short* __restrict__ xbf,
                                               const unsigned short* __restrict__ winbf,
                                               const float* __restrict__ b_in,
                                               unsigned short* __restrict__ xibf,
                                               unsigned short* __restrict__ resbf) {
  const int bid = blockIdx.x;                // 64 x 32 tiles
  gemm128<0>(xbf, winbf, 1024, (bid >> 5) * 128, (bid & 31) * 128, b_in,
             nullptr, xibf, resbf);
}

// K2: depthwise causal conv (K=4) + silu; xi bf16 -> xs bf16
__global__ __launch_bounds__(256) void k_conv(const unsigned short* __restrict__ xi,
                                              const float* __restrict__ cw,
                                              const float* __restrict__ cb,
                                              unsigned short* __restrict__ xs) {
  const int t = blockIdx.x * 256 + threadIdx.x;
  const int c4 = t & 511;                 // 512 channel-quads
  const int lc = (t >> 9) & 255;          // 256 l-chunks of 8
  const int b  = t >> 17;                 // 4 batches
  const int l0 = lc * 8;
  const int c0 = c4 * 4;
  const unsigned short* xb = xi + ((size_t)(b * 2048 + l0)) * 2048 + c0;
  u32x2 raw[11];
#pragma unroll
  for (int j = 0; j < 11; j++) {
    const int l = l0 + j - 3;
    raw[j] = (l >= 0) ? *(const u32x2*)(xb + ((long)j - 3) * 2048) : u32x2{0u, 0u};
  }
  f32x4 val[11];
#pragma unroll
  for (int j = 0; j < 11; j++) {
    val[j][0] = __uint_as_float(raw[j].x << 16);
    val[j][1] = __uint_as_float(raw[j].x & 0xFFFF0000u);
    val[j][2] = __uint_as_float(raw[j].y << 16);
    val[j][3] = __uint_as_float(raw[j].y & 0xFFFF0000u);
  }
  const f32x4 w0 = *(const f32x4*)(cw + (size_t)c0 * 4);
  const f32x4 w1 = *(const f32x4*)(cw + (size_t)(c0 + 1) * 4);
  const f32x4 w2 = *(const f32x4*)(cw + (size_t)(c0 + 2) * 4);
  const f32x4 w3 = *(const f32x4*)(cw + (size_t)(c0 + 3) * 4);
  const f32x4 bb = *(const f32x4*)(cb + c0);
  unsigned short* xp = xs + ((size_t)(b * 2048 + l0)) * 2048 + c0;
#pragma unroll
  for (int jo = 0; jo < 8; jo++) {
    f32x4 v;
    v[0] = bb[0] + w0[0]*val[jo][0] + w0[1]*val[jo+1][0] + w0[2]*val[jo+2][0] + w0[3]*val[jo+3][0];
    v[1] = bb[1] + w1[0]*val[jo][1] + w1[1]*val[jo+1][1] + w1[2]*val[jo+2][1] + w1[3]*val[jo+3][1];
    v[2] = bb[2] + w2[0]*val[jo][2] + w2[1]*val[jo+1][2] + w2[2]*val[jo+2][2] + w2[3]*val[jo+3][2];
    v[3] = bb[3] + w3[0]*val[jo][3] + w3[1]*val[jo+1][3] + w3[2]*val[jo+2][3] + w3[3]*val[jo+3][3];
#pragma unroll
    for (int q = 0; q < 4; q++) {
      const float x = v[q];
      v[q] = x * __builtin_amdgcn_rcpf(1.f + __expf(-x));   // silu
    }
    u32x2 rr;
    rr.x = (unsigned)f2bf(v[0]) | ((unsigned)f2bf(v[1]) << 16);
    rr.y = (unsigned)f2bf(v[2]) | ((unsigned)f2bf(v[3]) << 16);
    *(u32x2*)(xp + (size_t)jo * 2048) = rr;
  }
}

// K3: x_proj  bc = xs @ W_x^T + b_x   (M=8192, N=32, K=2048)
__global__ __launch_bounds__(256) void k_gemm2(const unsigned short* __restrict__ xs,
                                               const unsigned short* __restrict__ wx,
                                               const float* __restrict__ bx,
                                               float* __restrict__ bc) {
  __shared__ unsigned short As[128 * 64];
  __shared__ unsigned short Bs[32 * 64];
  const int tid = threadIdx.x, wave = tid >> 6, lane = tid & 63;
  const int m0 = blockIdx.x * 128;
  const int fr = lane & 15, k8 = (lane >> 4) << 3;
  f32x4 acc[2][2];
#pragma unroll
  for (int a = 0; a < 2; a++)
#pragma unroll
    for (int b = 0; b < 2; b++) acc[a][b] = f32x4{0.f, 0.f, 0.f, 0.f};

  for (int kt = 0; kt < 2048; kt += 64) {
#pragma unroll
    for (int i = 0; i < 4; i++) {
      const int base = (wave << 10) + (i << 12);
      const int off = base + (lane << 4);
      const int row = off >> 7, col = (off & 127) >> 1;
      gload_lds16(xs + (size_t)(m0 + row) * 2048 + kt + col, (char*)As + base);
    }
    {
      const int base = (wave << 10);
      const int off = base + (lane << 4);
      const int row = off >> 7, col = (off & 127) >> 1;
      gload_lds16(wx + (size_t)row * 2048 + kt + col, (char*)Bs + base);
    }
    __syncthreads();
#pragma unroll
    for (int kk = 0; kk < 2; kk++) {
      bf16x8 af[2], bfr[2];
#pragma unroll
      for (int f = 0; f < 2; f++) {
        af[f]  = *(const bf16x8*)&As[(wave * 32 + f * 16 + fr) * 64 + kk * 32 + k8];
        bfr[f] = *(const bf16x8*)&Bs[(f * 16 + fr) * 64 + kk * 32 + k8];
      }
#pragma unroll
      for (int fi = 0; fi < 2; fi++)
#pragma unroll
        for (int fj = 0; fj < 2; fj++)
          acc[fi][fj] = __builtin_amdgcn_mfma_f32_16x16x32_bf16(
              af[fi], bfr[fj], acc[fi][fj], 0, 0, 0);
    }
    __syncthreads();
  }
  const int r0 = (lane >> 4) * 4;
#pragma unroll
  for (int fi = 0; fi < 2; fi++)
#pragma unroll
    for (int fj = 0; fj < 2; fj++) {
      const int col = fj * 16 + fr;
      const float bia = bx[col];
#pragma unroll
      for (int r = 0; r < 4; r++) {
        const int row = m0 + wave * 32 + fi * 16 + r0 + r;
        bc[(size_t)row * 32 + col] = acc[fi][fj][r] + bia;
      }
    }
}

// ---------------- scan step (4 lanes per state) ----------------
// lane = 4*i + k; this lane's coef quad ax[r] = A_t[i][4k+r].
// gather h_{4k+r} via 4 bpermutes (addr base a0 = 64*(lane&3), loop-invariant),
// partial = sum_r ax[r]*g_r, quad butterfly (2 DPP adds), + B*h + C, tanh.
DEVFN float scan4_step(float h, const f32x4 ax, float Bt, float Ct, int a0) {
  const int hv = __float_as_int(h);
  const float g0 = __int_as_float(__builtin_amdgcn_ds_bpermute(a0,      hv));
  const float g1 = __int_as_float(__builtin_amdgcn_ds_bpermute(a0 + 16, hv));
  const float g2 = __int_as_float(__builtin_amdgcn_ds_bpermute(a0 + 32, hv));
  const float g3 = __int_as_float(__builtin_amdgcn_ds_bpermute(a0 + 48, hv));
  const float pa = fmaf(ax[1], g1, ax[0] * g0);
  const float pb = fmaf(ax[3], g3, ax[2] * g2);
  float p = pa + pb;
  p += DPPF(p, 0xB1);                  // + partial from lane^1
  p += DPPF(p, 0x4E);                  // + partials from lanes^2,^3
  const float s = p + fmaf(Bt, h, Ct);
  // tanh(s) = 1 - 2/(exp(2s)+1); exp->inf / ->0 give +-1 correctly
  const float e = __expf(2.f * s);
  return fmaf(-2.f, __builtin_amdgcn_rcpf(e + 1.f), 1.f);
}

// K4: fused  [blocks 0..511]: out = res_bf @ W_out^T   (MFMA)
//            [block 512]: 4 waves, wave b scans batch b -> hs
__global__ __launch_bounds__(256) void k4_gemm3_scan(
    const unsigned short* __restrict__ resbf, const unsigned short* __restrict__ woutbf,
    float* __restrict__ out, const float* __restrict__ bc, const float* __restrict__ dt,
    const float* __restrict__ Amat, float* __restrict__ hs) {
  if (blockIdx.x < 512) {
    const int bid = blockIdx.x;              // 64 x 8 tiles
    gemm128<1>(resbf, woutbf, 2048, (bid >> 3) * 128, (bid & 7) * 128, nullptr,
               out, nullptr, nullptr);
    return;
  }
  const int tid = threadIdx.x;
  const int b = tid >> 6;                    // wave = batch
  const int lane = tid & 63;
  const int i = lane >> 2, k = lane & 3;

  // register-resident coefficients for all 16 phases:
  // axv[p][r] = exp(exp(dt[p]) * A[i][4k+r])
  const f32x4 arow = *(const f32x4*)(Amat + i * 16 + k * 4);
  f32x4 axv[16];
#pragma unroll
  for (int p = 0; p < 16; p++) {
    const float e = __expf(dt[p]);
    axv[p][0] = __expf(e * arow[0]);
    axv[p][1] = __expf(e * arow[1]);
    axv[p][2] = __expf(e * arow[2]);
    axv[p][3] = __expf(e * arow[3]);
  }
  const int a0 = (lane & 3) << 6;            // bpermute byte base = 64*k
  const float* bcp = bc + (size_t)b * 65536 + i;   // B at [l*32+i], C at [l*32+16+i]
  float* hsp = hs + (size_t)b * 32768 + i;
  float h = 0.f;

  float p0B[8], p0C[8], p1B[8], p1C[8];
#pragma unroll
  for (int q = 0; q < 8; q++) { p0B[q] = bcp[q * 32]; p0C[q] = bcp[q * 32 + 16]; }

  for (int l0 = 0; l0 < 2048; l0 += 16) {
    {
      const float* bq = bcp + (size_t)(l0 + 8) * 32;
#pragma unroll
      for (int q = 0; q < 8; q++) { p1B[q] = bq[q * 32]; p1C[q] = bq[q * 32 + 16]; }
    }
#pragma unroll
    for (int q = 0; q < 8; q++) {
      h = scan4_step(h, axv[q], p0B[q], p0C[q], a0);
      if (k == 0) hsp[(size_t)(l0 + q) * 16] = h;
    }
    {
      const float* bq = bcp + (size_t)((l0 + 16) & 2047) * 32;  // wrap: last unused
#pragma unroll
      for (int q = 0; q < 8; q++) { p0B[q] = bq[q * 32]; p0C[q] = bq[q * 32 + 16]; }
    }
#pragma unroll
    for (int q = 8; q < 16; q++) {
      h = scan4_step(h, axv[q], p1B[q - 8], p1C[q - 8], a0);
      if (k == 0) hsp[(size_t)(l0 + q) * 16] = h;
    }
  }
}

// K5: out += b_out + hs @ W_red^T   (tile(hs,128) @ W_out^T == hs @ W_red^T)
__global__ __launch_bounds__(256) void k5_combine(float* __restrict__ out,
                                                  const float* __restrict__ hs,
                                                  const float* __restrict__ wred,
                                                  const float* __restrict__ bo) {
  const int m4 = threadIdx.x;      // 256 col-quads
  const int rg = blockIdx.x;       // 2048 row-quads
  f32x4 w[4][4];
#pragma unroll
  for (int mi = 0; mi < 4; mi++)
#pragma unroll
    for (int q = 0; q < 4; q++)
      w[mi][q] = *(const f32x4*)&wred[(size_t)(m4 * 4 + mi) * 16 + q * 4];
  const f32x4 bov = *(const f32x4*)&bo[m4 * 4];
#pragma unroll
  for (int r = 0; r < 4; r++) {
    const size_t row = (size_t)rg * 4 + r;
    f32x4 hv[4];
#pragma unroll
    for (int q = 0; q < 4; q++) hv[q] = *(const f32x4*)&hs[row * 16 + q * 4];
    float* op = out + row * 1024 + m4 * 4;
    f32x4 o = *(f32x4*)op;
#pragma unroll
    for (int mi = 0; mi < 4; mi++) {
      float v = bov[mi];
#pragma unroll
      for (int q = 0; q < 4; q++)
        v += w[mi][q][0]*hv[q][0] + w[mi][q][1]*hv[q][1] +
             w[mi][q][2]*hv[q][2] + w[mi][q][3]*hv[q][3];
      o[mi] += v;
    }
    *(f32x4*)op = o;
  }
}

extern "C" void kernel_launch(void* const* d_in, const int* in_sizes, int n_in,
                              void* d_out, int out_size, void* d_ws, size_t ws_size,
                              hipStream_t stream) {
  const float* x      = (const float*)d_in[0];
  const float* W_in   = (const float*)d_in[1];
  const float* b_in   = (const float*)d_in[2];
  const float* conv_w = (const float*)d_in[3];
  const float* conv_b = (const float*)d_in[4];
  const float* W_x    = (const float*)d_in[5];
  const float* b_x    = (const float*)d_in[6];
  const float* dt     = (const float*)d_in[7];
  const float* A      = (const float*)d_in[8];
  const float* W_out  = (const float*)d_in[10];
  const float* b_out  = (const float*)d_in[11];
  float* out = (float*)d_out;

  char* ws = (char*)d_ws;
  unsigned short* xbf    = (unsigned short*)(ws + OFF_XBF);
  unsigned short* winbf  = (unsigned short*)(ws + OFF_WINBF);
  unsigned short* wxbf   = (unsigned short*)(ws + OFF_WXBF);
  unsigned short* woutbf = (unsigned short*)(ws + OFF_WOUTBF);
  float*          wred   = (float*)(ws + OFF_WRED);
  unsigned short* xibf   = (unsigned short*)(ws + OFF_XIBF);
  unsigned short* resbf  = (unsigned short*)(ws + OFF_RESBF);
  unsigned short* xsbf   = (unsigned short*)(ws + OFF_XSBF);
  float*          bc     = (float*)(ws + OFF_BC);
  float*          hsb    = (float*)(ws + OFF_HS);

  k_prep<<<7264, 256, 0, stream>>>(x, W_in, W_x, W_out, xbf, winbf, wxbf, woutbf, wred);
  k_gemm1<<<2048, 256, 0, stream>>>(xbf, winbf, b_in, xibf, resbf);
  k_conv<<<2048, 256, 0, stream>>>(xibf, conv_w, conv_b, xsbf);
  k_gemm2<<<64, 256, 0, stream>>>(xsbf, wxbf, b_x, bc);
  k4_gemm3_scan<<<513, 256, 0, stream>>>(resbf, woutbf, out, bc, dt, A, hsb);
  k5_combine<<<2048, 256, 0, stream>>>(out, hsb, wred, b_out);
}